// Round 5
// baseline (1337.098 us; speedup 1.0000x reference)
//
#include <hip/hip_runtime.h>

// DETM forward. Round 11: theta1/x0 on a pipelined 128x128 fp32 GEMM.
//   R10 rocprof: theta1 gemm64 @136us (VALU 13%, HBM 7.8%, occ 23%) —
//   latency-bound: 64x64/4x4 tile = 8 FMA per ds_read_b128, no prefetch
//   (each of 14 K-steps exposes full load latency behind a barrier at 2.4
//   blocks/CU), 4-way ds_write bank conflicts (3.1M counted).
//   gemm128: 128x128 tile, 8x8 micro (16 FMA/ds_read_b128), BK=32,
//   register double-buffer (next K-tile loaded to VGPRs during compute),
//   Z=45 exact K-split. fp32 -> numerics unchanged. Applied to theta1+x0.

typedef unsigned int u32;
typedef unsigned short u16;
typedef _Float16 f16;
typedef f16 f16x2 __attribute__((ext_vector_type(2)));
typedef short bf16x8 __attribute__((ext_vector_type(8)));
typedef float f32x4 __attribute__((ext_vector_type(4)));
typedef u32 u32x4 __attribute__((ext_vector_type(4)));

#define LOG_DELTA (-5.2983174f)
#define COEFF 781.25f   // TRAIN_SIZE / B

#if defined(__has_builtin)
#if __has_builtin(__builtin_amdgcn_sdot4)
#define HAVE_SDOT4 1
#endif
#endif

__device__ __forceinline__ float bf2f(u16 a) { return __uint_as_float(((u32)a) << 16); }
__device__ __forceinline__ u16 f2bf(float f) {
  u32 u = __float_as_uint(f);
  u32 r = (u + 0x7fffu + ((u >> 16) & 1u)) >> 16;
  return (u16)r;
}
__device__ __forceinline__ int dot4i8(u32 a, u32 b, int c) {
#ifdef HAVE_SDOT4
  return __builtin_amdgcn_sdot4(a, b, c, false);
#else
  int s = c;
  s += ((int)(a << 24) >> 24) * ((int)(b << 24) >> 24);
  s += ((int)(a << 16) >> 24) * ((int)(b << 16) >> 24);
  s += ((int)(a << 8) >> 24) * ((int)(b << 8) >> 24);
  s += ((int)a >> 24) * ((int)b >> 24);
  return s;
#endif
}
__device__ __forceinline__ float sigm(float x) { return 1.f / (1.f + __expf(-x)); }
__device__ __forceinline__ float ftanh(float x) { float t = __expf(2.f * x); return (t - 1.f) / (t + 1.f); }
__device__ __forceinline__ u16 f2h(float x) { return __builtin_bit_cast(u16, (f16)x); }
__device__ __forceinline__ float h2f(u16 x) { return (float)__builtin_bit_cast(f16, x); }
__device__ __forceinline__ void async_load16(const u16* g, u16* l) {
  __builtin_amdgcn_global_load_lds((const __attribute__((address_space(1))) u32*)g,
                                   (__attribute__((address_space(3))) u32*)l, 16, 0, 0);
}

// ---------------- small utility kernels ----------------

__global__ __launch_bounds__(64) void k_zero(float* __restrict__ accum) {
  if (threadIdx.x < 8) accum[threadIdx.x] = 0.f;
}

__global__ __launch_bounds__(256) void k_nb(const float* __restrict__ bows, float* __restrict__ nb) {
  __shared__ float red[256];
  const int b = blockIdx.x, tid = threadIdx.x;
  float s = 0.f;
  for (int v = tid; v < 10000; v += 256) s += bows[b * 10000 + v];
  red[tid] = s; __syncthreads();
  for (int o = 128; o > 0; o >>= 1) { if (tid < o) red[tid] += red[tid + o]; __syncthreads(); }
  const float inv = 1.f / red[0];
  for (int v = tid; v < 10000; v += 256) nb[b * 10000 + v] = bows[b * 10000 + v] * inv;
}

__global__ __launch_bounds__(256) void k_bsum(const float* __restrict__ a, const float* __restrict__ b,
                                              float* __restrict__ o, int n) {
  int i = blockIdx.x * 256 + threadIdx.x;
  if (i < n) o[i] = a[i] + b[i];
}

__global__ __launch_bounds__(256) void k_fill(float* __restrict__ C, const float* __restrict__ bias,
                                              int N, int total) {
  for (int i = blockIdx.x * 256 + threadIdx.x; i < total; i += gridDim.x * 256)
    C[i] = bias[i % N];
}

__global__ __launch_bounds__(256) void k_relu(float* __restrict__ C, int total) {
  for (int i = blockIdx.x * 256 + threadIdx.x; i < total; i += gridDim.x * 256) {
    float v = C[i];
    C[i] = v > 0.f ? v : 0.f;
  }
}

// stack two 50-vectors into one 100-vector
__global__ __launch_bounds__(128) void k_stack2(const float* __restrict__ a, const float* __restrict__ b,
                                                float* __restrict__ o) {
  const int t = threadIdx.x;
  if (t < 50) o[t] = a[t];
  else if (t < 100) o[t] = b[t - 50];
}

// quantize Whh rows to int8, row-major layout whq[layer][row][52 dwords]
__global__ __launch_bounds__(64) void k_quant_whh(const float* __restrict__ Whh,
                                                  u32* __restrict__ whq, float* __restrict__ rowscale) {
  const int gr = blockIdx.x;          // 0..2399
  const int lane = threadIdx.x;
  __shared__ float wrow[200];
  const float* src = Whh + (size_t)gr * 200;
  float m = 0.f;
  for (int c = lane; c < 200; c += 64) { float v = src[c]; wrow[c] = v; m = fmaxf(m, fabsf(v)); }
  for (int o = 32; o > 0; o >>= 1) m = fmaxf(m, __shfl_down(m, o));
  m = __shfl(m, 0);
  const float qs = (m > 0.f) ? 127.f / m : 0.f;
  __syncthreads();
  const int l = gr / 800, rr = gr - l * 800;
  if (lane < 52) {
    u32 d = 0;
    if (lane < 50) {
#pragma unroll
      for (int b = 0; b < 4; ++b) {
        int q = __float2int_rn(wrow[lane * 4 + b] * qs);
        q = max(-127, min(127, q));
        d |= ((u32)(q & 0xff)) << (8 * b);
      }
    }
    whq[l * 41600 + rr * 52 + lane] = d;
  }
  if (lane == 0) rowscale[gr] = (m > 0.f) ? m / 127.f : 0.f;
}

// bf16 staging for the beta MFMA GEMM
__global__ __launch_bounds__(256) void k_prep_A(const float* __restrict__ muq, u16* __restrict__ Abf) {
  int idx = blockIdx.x * 256 + threadIdx.x;
  if (idx >= 5120 * 320) return;
  int r = idx % 320, m = idx / 320;
  float v = 0.f;
  if (r < 300 && m < 5000) { int t = m / 50, k = m - t * 50; v = muq[k * 30000 + t * 300 + r]; }
  Abf[idx] = f2bf(v);
}
__global__ __launch_bounds__(256) void k_prep_B(const float* __restrict__ rho, u16* __restrict__ Bbf) {
  int idx = blockIdx.x * 256 + threadIdx.x;
  if (idx >= 10112 * 320) return;
  int r = idx % 320, n = idx / 320;
  float v = (r < 300 && n < 10000) ? rho[n * 300 + r] : 0.f;
  Bbf[idx] = f2bf(v);
}

// ---------------- fp32 GEMM, 64x64 tile: C[M,N] = A[M,K] @ B[N,K]^T ----------------

#define ST 64
#define SBK 32

template<int AMODE, int BMODE, int EPI>
__global__ __launch_bounds__(256) void gemm64(
    const float* __restrict__ A, const float* __restrict__ Bm, const float* __restrict__ Bm2,
    const float* __restrict__ bias, float* __restrict__ C,
    int M, int N, int Kd, int lda, int ldb,
    const int* __restrict__ times, const float* __restrict__ etas)
{
  __shared__ __align__(16) float As[SBK][ST + 4];   // row stride 272B = 16B-aligned
  __shared__ __align__(16) float Bs[SBK][ST + 4];
  const int tid = threadIdx.x;
  const int tx = tid & 15, ty = tid >> 4;
  const int m_base = blockIdx.x * ST, n_base = blockIdx.y * ST;
  float acc[4][4] = {};
  const int nkt = (Kd + SBK - 1) / SBK;
  const int per = (nkt + gridDim.z - 1) / gridDim.z;
  const int kt0 = blockIdx.z * per;
  const int kt1 = min(nkt, kt0 + per);
  const int lkk = tid & 31;      // k within tile (consecutive lanes -> coalesced global)
  const int lrow = tid >> 5;     // 0..7
  for (int kt = kt0; kt < kt1; ++kt) {
    const int kg = kt * SBK + lkk;
#pragma unroll
    for (int i = 0; i < 8; ++i) {
      const int m = m_base + lrow + i * 8;
      float v = 0.f;
      if (m < M && kg < Kd) {
        if (AMODE == 0) v = A[(size_t)m * lda + kg];
        else {
          if (kg < 10000) v = A[(size_t)m * 10000 + kg];
          else v = etas[times[m] * 50 + (kg - 10000)];
        }
      }
      As[lkk][lrow + i * 8] = v;
    }
#pragma unroll
    for (int i = 0; i < 8; ++i) {
      const int n = n_base + lrow + i * 8;
      float v = 0.f;
      if (n < N && kg < Kd) {
        if (BMODE == 0) v = Bm[(size_t)n * ldb + kg];
        else v = (n < 50) ? Bm[(size_t)n * ldb + kg] : Bm2[(size_t)(n - 50) * ldb + kg];
      }
      Bs[lkk][lrow + i * 8] = v;
    }
    __syncthreads();
#pragma unroll
    for (int kk = 0; kk < SBK; ++kk) {
      const float4 a4 = *(const float4*)&As[kk][ty * 4];
      const float4 b4 = *(const float4*)&Bs[kk][tx * 4];
      const float av[4] = {a4.x, a4.y, a4.z, a4.w};
      const float bv[4] = {b4.x, b4.y, b4.z, b4.w};
#pragma unroll
      for (int i = 0; i < 4; ++i)
#pragma unroll
        for (int j = 0; j < 4; ++j) acc[i][j] += av[i] * bv[j];
    }
    __syncthreads();
  }
#pragma unroll
  for (int i = 0; i < 4; ++i) {
    const int m = m_base + ty * 4 + i;
    if (m >= M) continue;
#pragma unroll
    for (int j = 0; j < 4; ++j) {
      const int n = n_base + tx * 4 + j;
      if (n >= N) continue;
      float v = acc[i][j];
      if (EPI == 1) { C[(size_t)m * N + n] = v + bias[n]; }
      else if (EPI == 2) { v += bias[n]; C[(size_t)m * N + n] = v > 0.f ? v : 0.f; }
      else if (EPI == 5) { atomicAdd(&C[(size_t)m * N + n], v); }
      else { C[(size_t)m * N + n] = v; }
    }
  }
}

// ---------------- fp32 GEMM, 128x128 tile, 8x8 micro, reg-prefetch ----------------
// C[M,N] += A[M,K] @ B[N,K]^T via atomicAdd (split-K over gridDim.z).
// Register double-buffer: kt+1's 32 staging values load into VGPRs right
// after the barrier; waitcnt lands before next iteration's LDS writes ->
// global latency hides under the 2048-FMA compute phase.

#define LT 128
#define LBK 32

template<int AMODE>
__global__ __launch_bounds__(256) void gemm128(
    const float* __restrict__ A, const float* __restrict__ Bm,
    float* __restrict__ C,
    int M, int N, int Kd, int lda, int ldb,
    const int* __restrict__ times, const float* __restrict__ etas)
{
  __shared__ __align__(16) float As[LBK][LT + 4];   // row stride 528B = 16B-aligned
  __shared__ __align__(16) float Bs[LBK][LT + 4];
  const int tid = threadIdx.x;
  const int tx = tid & 15, ty = tid >> 4;
  const int m_base = blockIdx.x * LT, n_base = blockIdx.y * LT;
  const int nkt = (Kd + LBK - 1) / LBK;
  const int per = (nkt + gridDim.z - 1) / gridDim.z;
  const int kt0 = blockIdx.z * per;
  const int kt1 = min(nkt, kt0 + per);
  if (kt0 >= kt1) return;          // uniform early-exit (before any barrier)
  const int lkk = tid & 31;        // k within tile (coalesced global)
  const int lrow = tid >> 5;       // 0..7
  float acc[8][8] = {};
  float pa[16], pb[16];
  {
    const int kg = kt0 * LBK + lkk;
#pragma unroll
    for (int i = 0; i < 16; ++i) {
      const int m = m_base + lrow + i * 8;
      float v = 0.f;
      if (m < M && kg < Kd) {
        if (AMODE == 0) v = A[(size_t)m * lda + kg];
        else v = (kg < 10000) ? A[(size_t)m * 10000 + kg] : etas[times[m] * 50 + (kg - 10000)];
      }
      pa[i] = v;
      const int n = n_base + lrow + i * 8;
      float w = 0.f;
      if (n < N && kg < Kd) w = Bm[(size_t)n * ldb + kg];
      pb[i] = w;
    }
  }
  for (int kt = kt0; kt < kt1; ++kt) {
#pragma unroll
    for (int i = 0; i < 16; ++i) {
      As[lkk][lrow + i * 8] = pa[i];
      Bs[lkk][lrow + i * 8] = pb[i];
    }
    __syncthreads();
    if (kt + 1 < kt1) {
      const int kg = (kt + 1) * LBK + lkk;
#pragma unroll
      for (int i = 0; i < 16; ++i) {
        const int m = m_base + lrow + i * 8;
        float v = 0.f;
        if (m < M && kg < Kd) {
          if (AMODE == 0) v = A[(size_t)m * lda + kg];
          else v = (kg < 10000) ? A[(size_t)m * 10000 + kg] : etas[times[m] * 50 + (kg - 10000)];
        }
        pa[i] = v;
        const int n = n_base + lrow + i * 8;
        float w = 0.f;
        if (n < N && kg < Kd) w = Bm[(size_t)n * ldb + kg];
        pb[i] = w;
      }
    }
#pragma unroll
    for (int kk = 0; kk < LBK; ++kk) {
      const float4* ap = (const float4*)&As[kk][ty * 8];
      const float4* bp = (const float4*)&Bs[kk][tx * 8];
      const float4 a0 = ap[0], a1 = ap[1];
      const float4 b0 = bp[0], b1 = bp[1];
      const float av[8] = {a0.x, a0.y, a0.z, a0.w, a1.x, a1.y, a1.z, a1.w};
      const float bv[8] = {b0.x, b0.y, b0.z, b0.w, b1.x, b1.y, b1.z, b1.w};
#pragma unroll
      for (int i = 0; i < 8; ++i)
#pragma unroll
        for (int j = 0; j < 8; ++j) acc[i][j] += av[i] * bv[j];
    }
    __syncthreads();
  }
#pragma unroll
  for (int i = 0; i < 8; ++i) {
    const int m = m_base + ty * 8 + i;
    if (m >= M) continue;
#pragma unroll
    for (int j = 0; j < 8; ++j) {
      const int n = n_base + tx * 8 + j;
      if (n >= N) continue;
      atomicAdd(&C[(size_t)m * N + n], acc[i][j]);
    }
  }
}

// ---------------- beta GEMM: bf16 MFMA ----------------

__global__ __launch_bounds__(256) void gemm_mfma_bT(
    const u16* __restrict__ A, const u16* __restrict__ B, u16* __restrict__ C,
    int M, int N)
{
  __shared__ u16 As[128 * 32];
  __shared__ u16 Bs[128 * 32];
  const int tid = threadIdx.x;
  const int l = tid & 63, w = tid >> 6;
  const int wm = w & 1, wn = w >> 1;
  const int m0 = blockIdx.x * 128, n0 = blockIdx.y * 128;
  f32x4 acc[4][4] = {};
  const int arow = l >> 2;
  const int acol = (l & 3) * 8;
  for (int kt = 0; kt < 10; ++kt) {
    const int k0 = kt * 32;
#pragma unroll
    for (int c = 0; c < 2; ++c) {
      const int i = w + c * 4;
      async_load16(A + (size_t)(m0 + i * 16 + arow) * 320 + k0 + acol, As + i * 512);
      async_load16(B + (size_t)(n0 + i * 16 + arow) * 320 + k0 + acol, Bs + i * 512);
    }
    __syncthreads();
    bf16x8 af[4], bfr[4];
#pragma unroll
    for (int x = 0; x < 4; ++x) {
      af[x]  = *(const bf16x8*)&As[(wm * 64 + x * 16 + (l & 15)) * 32 + (l >> 4) * 8];
      bfr[x] = *(const bf16x8*)&Bs[(wn * 64 + x * 16 + (l & 15)) * 32 + (l >> 4) * 8];
    }
#pragma unroll
    for (int x = 0; x < 4; ++x)
#pragma unroll
      for (int y = 0; y < 4; ++y)
        acc[x][y] = __builtin_amdgcn_mfma_f32_16x16x32_bf16(af[x], bfr[y], acc[x][y], 0, 0, 0);
    __syncthreads();
  }
  const int col = l & 15, quad = l >> 4;
#pragma unroll
  for (int x = 0; x < 4; ++x) {
    const int gmB = m0 + wm * 64 + x * 16 + quad * 4;
#pragma unroll
    for (int y = 0; y < 4; ++y) {
      const int gn = n0 + wn * 64 + y * 16 + col;
      if (gn >= N) continue;
#pragma unroll
      for (int r = 0; r < 4; ++r) {
        const int gm = gmB + r;
        if (gm < M) C[(size_t)gm * N + gn] = f2bf(acc[x][y][r]);
      }
    }
  }
}

// ---------------- LSTM scan: int8 weights REGISTER-resident ----------------

__global__ __launch_bounds__(512, 1) void lstm_scan_reg(
    const u32* __restrict__ whq,       // [800][52] row-major this layer
    const float* __restrict__ rowscale,// [800] this layer
    const float* __restrict__ xproj,   // [100][800]
    float* __restrict__ hseq)          // [100][200]
{
  __shared__ u16 pg[800];                 // gate pre-acts f16
  __shared__ __align__(16) u32 hq[52];    // h int8 packed (200 vals + pad)
  __shared__ float wmax[8];
  __shared__ float hscale_s[1];
  const int tid = threadIdx.x;
  const int act = (tid < 400);
  const int r0 = tid, r1 = tid + 400;
  u32x4 wA4[13], wB4[13];
  float rsA = 0.f, rsB = 0.f;
  float xpA = 0.f, xpB = 0.f;
  if (act) {
    const u32x4* gA = (const u32x4*)(whq + (size_t)r0 * 52);
    const u32x4* gB = (const u32x4*)(whq + (size_t)r1 * 52);
#pragma unroll
    for (int i = 0; i < 13; ++i) { wA4[i] = gA[i]; wB4[i] = gB[i]; }
    rsA = rowscale[r0]; rsB = rowscale[r1];
    xpA = xproj[r0]; xpB = xproj[r1];
  }
  if (tid < 52) hq[tid] = 0;
  if (tid < 8) wmax[tid] = 0.f;
  if (tid == 0) hscale_s[0] = 0.f;
  float c_reg = 0.f;
  __syncthreads();
  for (int t = 0; t < 100; ++t) {
    if (act) {
      float nxA = 0.f, nxB = 0.f;
      if (t < 99) { nxA = xproj[(t + 1) * 800 + r0]; nxB = xproj[(t + 1) * 800 + r1]; }
      const float hdq = hscale_s[0];
      u32x4 hv4[13];
#pragma unroll
      for (int i = 0; i < 13; ++i) hv4[i] = *((const u32x4*)hq + i);
      int aA = 0, aB = 0;
#pragma unroll
      for (int g = 0; g < 50; ++g) {
        const u32 h = hv4[g >> 2][g & 3];
        aA = dot4i8(wA4[g >> 2][g & 3], h, aA);
        aB = dot4i8(wB4[g >> 2][g & 3], h, aB);
      }
      pg[r0] = f2h((float)aA * (rsA * hdq) + xpA);
      pg[r1] = f2h((float)aB * (rsB * hdq) + xpB);
      xpA = nxA; xpB = nxB;
    }
    __syncthreads();   // pg ready; all lanes done reading hq/hscale
    float hv = 0.f;
    if (tid < 200) {
      float gi = sigm(h2f(pg[tid]));
      float gf = sigm(h2f(pg[200 + tid]));
      float gg = ftanh(h2f(pg[400 + tid]));
      float go = sigm(h2f(pg[600 + tid]));
      c_reg = gf * c_reg + gi * gg;
      hv = go * ftanh(c_reg);
      hseq[t * 200 + tid] = hv;
    }
    // block-wide max|h| (only waves 0-3 hold h; others contribute 0)
    float m = fabsf(hv);
    for (int o = 32; o > 0; o >>= 1) m = fmaxf(m, __shfl_down(m, o));
    if ((tid & 63) == 0) wmax[tid >> 6] = m;
    __syncthreads();   // wmax ready, pg consumed
    if (tid < 200) {
      const float hm = fmaxf(fmaxf(wmax[0], wmax[1]), fmaxf(wmax[2], wmax[3]));
      const float qs = (hm > 0.f) ? 127.f / hm : 0.f;
      int q = __float2int_rn(hv * qs);
      q = max(-127, min(127, q));
      ((signed char*)hq)[tid] = (signed char)q;
      if (tid == 0) hscale_s[0] = (hm > 0.f) ? hm / 127.f : 0.f;
    }
    __syncthreads();   // hq + hscale ready for next step
  }
}

// ---------------- eta scan: 50-col recurrent tail, ONE wave ----------------

__global__ __launch_bounds__(64, 1) void eta_scan_reg(
    const float* __restrict__ muW, const float* __restrict__ lsW,  // [50][250] fp32
    const float* __restrict__ pc0,   // [100][100] (bias included)
    float* __restrict__ etas, float* __restrict__ accum)
{
  __shared__ __align__(16) float ep[52];
  const int j = threadIdx.x;
  const int act = (j < 50);
  float wmu[52], wls[52];
  if (act) {
#pragma unroll
    for (int k = 0; k < 25; ++k) {   // rows start at j*250+200: even offset -> 8B aligned
      float2 a = *(const float2*)(muW + (size_t)j * 250 + 200 + 2 * k);
      float2 b = *(const float2*)(lsW + (size_t)j * 250 + 200 + 2 * k);
      wmu[2 * k] = a.x; wmu[2 * k + 1] = a.y;
      wls[2 * k] = b.x; wls[2 * k + 1] = b.y;
    }
    wmu[50] = wmu[51] = wls[50] = wls[51] = 0.f;
  } else {
#pragma unroll
    for (int k = 0; k < 52; ++k) { wmu[k] = 0.f; wls[k] = 0.f; }
  }
  if (j < 52) ep[j] = 0.f;
  float klacc = 0.f;
  float mye = 0.f;                       // this lane's eta_prev
  float pmu = act ? pc0[j] : 0.f;        // prefetched pc0 row t
  float pls_ = act ? pc0[50 + j] : 0.f;
  __syncthreads();
  for (int t = 0; t < 100; ++t) {
    float nmu = 0.f, nls = 0.f;
    if (act && t < 99) { nmu = pc0[(t + 1) * 100 + j]; nls = pc0[(t + 1) * 100 + 50 + j]; }
    float ma[4] = {pmu, 0.f, 0.f, 0.f};
    float la[4] = {pls_, 0.f, 0.f, 0.f};
    const float4* e4 = (const float4*)ep;
#pragma unroll
    for (int i = 0; i < 13; ++i) {
      const float4 e = e4[i];
      ma[0] += wmu[4 * i + 0] * e.x; ma[1] += wmu[4 * i + 1] * e.y;
      ma[2] += wmu[4 * i + 2] * e.z; ma[3] += wmu[4 * i + 3] * e.w;
      la[0] += wls[4 * i + 0] * e.x; la[1] += wls[4 * i + 1] * e.y;
      la[2] += wls[4 * i + 2] * e.z; la[3] += wls[4 * i + 3] * e.w;
    }
    const float mu = (ma[0] + ma[1]) + (ma[2] + ma[3]);
    const float ls = (la[0] + la[1]) + (la[2] + la[3]);
    __syncthreads();   // all lanes done reading ep (lockstep anyway; fence)
    if (act) {
      const float pls = (t == 0) ? 0.f : LOG_DELTA;
      const float pv = __expf(pls) + 1e-6f;
      const float d = mu - mye;
      klacc += 0.5f * ((__expf(ls) + d * d) / pv - 1.f + pls - ls);
      etas[t * 50 + j] = mu;
      mye = mu;
      ep[j] = mu;
    }
    __syncthreads();   // ep ready for next step
    pmu = nmu; pls_ = nls;
  }
  for (int o = 32; o > 0; o >>= 1) klacc += __shfl_down(klacc, o);
  if (j == 0) accum[0] = klacc;
}

// ---------------- theta head (reads stacked [128][100] mu|ls) ----------------

__global__ __launch_bounds__(64) void k_theta(const float* __restrict__ mul,
                                              const float* __restrict__ etas, const int* __restrict__ times,
                                              float* __restrict__ theta, float* __restrict__ accum) {
  const int b = blockIdx.x, lane = threadIdx.x;
  float m_ = 0.f, l_ = 0.f, e_ = 0.f, mx = -1e30f;
  if (lane < 50) {
    m_ = mul[b * 100 + lane];
    l_ = mul[b * 100 + 50 + lane];
    e_ = etas[times[b] * 50 + lane];
    mx = m_;
  }
  for (int o = 32; o > 0; o >>= 1) mx = fmaxf(mx, __shfl_down(mx, o));
  mx = __shfl(mx, 0);
  float ex = (lane < 50) ? __expf(m_ - mx) : 0.f;
  float sum = ex;
  for (int o = 32; o > 0; o >>= 1) sum += __shfl_down(sum, o);
  sum = __shfl(sum, 0);
  if (lane < 50) theta[b * 50 + lane] = ex / sum;
  float kl = 0.f;
  if (lane < 50) {
    float d = m_ - e_;
    kl = 0.5f * ((__expf(l_) + d * d) / (1.f + 1e-6f) - 1.f - l_);
  }
  for (int o = 32; o > 0; o >>= 1) kl += __shfl_down(kl, o);
  if (lane == 0) atomicAdd(accum + 1, kl);
}

// ---------------- softmax denominators ----------------

__global__ __launch_bounds__(256) void k_rowsum(const u16* __restrict__ logit, float* __restrict__ Z) {
  const int r = blockIdx.x, tid = threadIdx.x;
  const u32* row = (const u32*)(logit + (size_t)r * 10000);
  __shared__ float red[256];
  float s = 0.f;
  for (int v = tid; v < 5000; v += 256) {
    u32 p = row[v];
    s += __expf(bf2f((u16)(p & 0xffffu))) + __expf(bf2f((u16)(p >> 16)));
  }
  red[tid] = s; __syncthreads();
  for (int o = 128; o > 0; o >>= 1) { if (tid < o) red[tid] += red[tid + o]; __syncthreads(); }
  if (tid == 0) Z[r] = red[0];
}

// ---------------- NLL ----------------

__global__ __launch_bounds__(256) void k_nll(const u16* __restrict__ logit, const float* __restrict__ Z,
                                             const float* __restrict__ theta, const float* __restrict__ bows,
                                             const int* __restrict__ times, float* __restrict__ accum) {
  const int b = blockIdx.x, seg = blockIdx.y, tid = threadIdx.x;
  const int t = times[b];
  __shared__ float c2[52];
  __shared__ float red[256];
  if (tid < 50) c2[tid] = theta[b * 50 + tid] / Z[t * 50 + tid];
  __syncthreads();
  float part = 0.f;
  const int v0 = seg * 1250, v1 = v0 + 1250;
  const u16* base = logit + (size_t)t * 500000;
  for (int v = v0 + tid; v < v1; v += 256) {
    float ssv = 1e-12f;
#pragma unroll
    for (int k = 0; k < 50; ++k) ssv += c2[k] * __expf(bf2f(base[k * 10000 + v]));
    part += bows[b * 10000 + v] * __logf(ssv);
  }
  red[tid] = part; __syncthreads();
  for (int o = 128; o > 0; o >>= 1) { if (tid < o) red[tid] += red[tid + o]; __syncthreads(); }
  if (tid == 0) atomicAdd(accum + 3, -red[0]);
}

// ---------------- kl_alpha ----------------

__global__ __launch_bounds__(256) void k_alpha_kl(const float* __restrict__ muq, const float* __restrict__ lsq,
                                                  float* __restrict__ accum) {
  __shared__ float red[256];
  const int tid = threadIdx.x;
  float s = 0.f;
  for (int i = blockIdx.x * 256 + tid; i < 1500000; i += gridDim.x * 256) {
    int r = i % 300;
    int tk = i / 300;
    int k = tk % 50;
    int t = tk / 50;
    size_t idx = (size_t)k * 30000 + (size_t)t * 300 + r;
    float mu = muq[idx], ls = lsq[idx];
    float pm = 0.f, pls = 0.f;
    if (t > 0) { pm = muq[idx - 300]; pls = LOG_DELTA; }
    float d = mu - pm;
    s += 0.5f * ((__expf(ls) + d * d) / (__expf(pls) + 1e-6f) - 1.f + pls - ls);
  }
  red[tid] = s; __syncthreads();
  for (int o = 128; o > 0; o >>= 1) { if (tid < o) red[tid] += red[tid + o]; __syncthreads(); }
  if (tid == 0) atomicAdd(accum + 2, red[0]);
}

// ---------------- final combine ----------------

__global__ __launch_bounds__(64) void k_final(const float* __restrict__ accum, float* __restrict__ out) {
  if (threadIdx.x == 0) {
    float nll = accum[3] * COEFF;
    float kl_eta = accum[0];
    float kl_theta = accum[1] * COEFF;
    float kl_alpha = accum[2];
    out[0] = nll + kl_eta + kl_theta + kl_alpha;
    out[1] = nll;
    out[2] = kl_eta;
    out[3] = kl_theta;
    out[4] = kl_alpha;
  }
}

// ---------------- launcher ----------------

extern "C" void kernel_launch(void* const* d_in, const int* in_sizes, int n_in,
                              void* d_out, int out_size, void* d_ws, size_t ws_size,
                              hipStream_t stream) {
  (void)in_sizes; (void)n_in; (void)out_size; (void)ws_size;
  const float* bows   = (const float*)d_in[0];
  const int*   times  = (const int*)d_in[1];
  const float* rnn_in = (const float*)d_in[2];
  const float* rho_W  = (const float*)d_in[3];
  const float* muq    = (const float*)d_in[4];
  const float* lsq    = (const float*)d_in[5];
  const float* qW1    = (const float*)d_in[6];
  const float* qb1    = (const float*)d_in[7];
  const float* qW2    = (const float*)d_in[8];
  const float* qb2    = (const float*)d_in[9];
  const float* muthW  = (const float*)d_in[10];
  const float* muthb  = (const float*)d_in[11];
  const float* lsthW  = (const float*)d_in[12];
  const float* lsthb  = (const float*)d_in[13];
  const float* emW    = (const float*)d_in[14];
  const float* emb    = (const float*)d_in[15];
  const float* Wih    = (const float*)d_in[16];
  const float* Whh    = (const float*)d_in[17];
  const float* bih    = (const float*)d_in[18];
  const float* bhh    = (const float*)d_in[19];
  const float* mueW   = (const float*)d_in[20];
  const float* mueb   = (const float*)d_in[21];
  const float* lseW   = (const float*)d_in[22];
  const float* lseb   = (const float*)d_in[23];
  float* out = (float*)d_out;
  float* ws = (float*)d_ws;

  float* accum = ws + 0;
  float* nb    = ws + 8;
  float* x0    = ws + 1280008;
  float* xproj = ws + 1300008;
  float* hsA   = ws + 1380008;
  float* hsB   = ws + 1400008;
  u32*   whq   = (u32*)(ws + 1420008);         // 124,800 u32 (3 layers, [800][52])
  float* rowsc = ws + 1544808;                 // 2400
  float* bias2 = ws + 1547208;                 // 100 (stacked mu/ls theta bias)
  float* pc0   = ws + 1547408;                 // [100][100] eta-head o_t part
  float* bias2e= ws + 1558008;                 // 100 (stacked eta-head bias)
  float* hsC   = ws + 1560008;                 // 20,000
  float* bsum  = ws + 1660008;
  float* etas  = ws + 1662408;
  float* h1    = ws + 1667408;
  float* h2    = ws + 1769808;
  float* mul   = ws + 1872208;                 // [128][100] stacked mu_t|ls_t
  float* theta = ws + 1885008;
  float* Zrow  = ws + 1891408;
  u16*   A_bf  = (u16*)(ws + 1896408);
  u16*   B_bf  = (u16*)(ws + 2715608);
  u16*   logit = (u16*)(ws + 4333528);

  k_zero<<<1, 64, 0, stream>>>(accum);
  k_nb<<<128, 256, 0, stream>>>(bows, nb);
  k_quant_whh<<<2400, 64, 0, stream>>>(Whh, whq, rowsc);
  k_bsum<<<10, 256, 0, stream>>>(bih, bhh, bsum, 2400);
  k_prep_A<<<6400, 256, 0, stream>>>(muq, A_bf);
  k_prep_B<<<12640, 256, 0, stream>>>(rho_W, B_bf);
  k_stack2<<<1, 128, 0, stream>>>(muthb, lsthb, bias2);
  k_stack2<<<1, 128, 0, stream>>>(mueb, lseb, bias2e);
  k_fill<<<40, 256, 0, stream>>>(pc0, bias2e, 100, 10000);

  // x0 = rnn_inp @ eta_map_W^T + eta_map_b   (pipelined 128-tile, K-split)
  k_fill<<<79, 256, 0, stream>>>(x0, emb, 200, 20000);
  gemm128<0><<<dim3(1, 2, 104), 256, 0, stream>>>(rnn_in, emW, x0,
                                                  100, 200, 10000, 10000, 10000, nullptr, nullptr);

  // LSTM layers (register-resident int8 scans)
  const float* lin[3] = {x0, hsA, hsB};
  float* lout[3] = {hsA, hsB, hsC};
  for (int l = 0; l < 3; ++l) {
    gemm64<0, 0, 1><<<dim3(2, 13, 1), 256, 0, stream>>>(lin[l], Wih + l * 160000, nullptr,
                                                        bsum + l * 800, xproj,
                                                        100, 800, 200, 200, 200, nullptr, nullptr);
    lstm_scan_reg<<<1, 512, 0, stream>>>(whq + l * 41600, rowsc + l * 800, xproj, lout[l]);
  }
  // eta head: parallel o_t GEMM (pc0 += hsC @ W[:, :200]^T), then 1-wave scan
  gemm64<0, 1, 5><<<dim3(2, 2, 7), 256, 0, stream>>>(hsC, mueW, lseW, nullptr, pc0,
                                                     100, 100, 200, 200, 250, nullptr, nullptr);
  eta_scan_reg<<<1, 64, 0, stream>>>(mueW, lseW, pc0, etas, accum);

  // theta encoder
  k_fill<<<400, 256, 0, stream>>>(h1, qb1, 800, 102400);
  gemm128<2><<<dim3(1, 7, 45), 256, 0, stream>>>(nb, qW1, h1,
                                                 128, 800, 10050, 10000, 10050, times, etas);
  k_relu<<<400, 256, 0, stream>>>(h1, 102400);
  k_fill<<<400, 256, 0, stream>>>(h2, qb2, 800, 102400);
  gemm64<0, 0, 5><<<dim3(2, 13, 4), 256, 0, stream>>>(h1, qW2, nullptr, nullptr, h2,
                                                      128, 800, 800, 800, 800, nullptr, nullptr);
  k_relu<<<400, 256, 0, stream>>>(h2, 102400);
  // fused mu/ls head -> stacked [128][100]
  k_fill<<<50, 256, 0, stream>>>(mul, bias2, 100, 12800);
  gemm64<0, 1, 5><<<dim3(2, 2, 5), 256, 0, stream>>>(h2, muthW, lsthW, nullptr, mul,
                                                     128, 100, 800, 800, 800, nullptr, nullptr);
  k_theta<<<128, 64, 0, stream>>>(mul, etas, times, theta, accum);

  // beta logits (bf16 MFMA) + softmax denominators + NLL
  gemm_mfma_bT<<<dim3(40, 79), 256, 0, stream>>>(A_bf, B_bf, logit, 5000, 10000);
  k_rowsum<<<5000, 256, 0, stream>>>(logit, Zrow);
  k_nll<<<dim3(128, 8), 256, 0, stream>>>(logit, Zrow, theta, bows, times, accum);

  k_alpha_kl<<<512, 256, 0, stream>>>(muq, lsq, accum);
  k_final<<<1, 64, 0, stream>>>(accum, out);
}

// Round 6
// 1109.211 us; speedup vs baseline: 1.2054x; 1.2054x over previous
//
#include <hip/hip_runtime.h>

// DETM forward. Round 12: split-K via partial buffers, not atomics.
//   R11 post-mortem: gemm128 theta1 @231us, WRITE_SIZE=144MB (8x the logical
//   18.4MB) — every scattered 4B atomicAdd costs a ~32B memory-side sector
//   RMW (per-XCD L2 non-coherent -> device atomics punch to memory side).
//   Split-K accumulation was the bottleneck, not the GEMM core.
//   Now: gemm128p stores each z-slice's partials to a private buffer with
//   plain coalesced stores; k_reduceZ sums slices + bias (+ReLU fused).
//   Partials alias the (later-written) logit region. Applied to theta1
//   (Z=45), x0 (Z=64), theta2 (Z=5). Empty-K blocks store zeros (no init).

typedef unsigned int u32;
typedef unsigned short u16;
typedef _Float16 f16;
typedef f16 f16x2 __attribute__((ext_vector_type(2)));
typedef short bf16x8 __attribute__((ext_vector_type(8)));
typedef float f32x4 __attribute__((ext_vector_type(4)));
typedef u32 u32x4 __attribute__((ext_vector_type(4)));

#define LOG_DELTA (-5.2983174f)
#define COEFF 781.25f   // TRAIN_SIZE / B

#if defined(__has_builtin)
#if __has_builtin(__builtin_amdgcn_sdot4)
#define HAVE_SDOT4 1
#endif
#endif

__device__ __forceinline__ float bf2f(u16 a) { return __uint_as_float(((u32)a) << 16); }
__device__ __forceinline__ u16 f2bf(float f) {
  u32 u = __float_as_uint(f);
  u32 r = (u + 0x7fffu + ((u >> 16) & 1u)) >> 16;
  return (u16)r;
}
__device__ __forceinline__ int dot4i8(u32 a, u32 b, int c) {
#ifdef HAVE_SDOT4
  return __builtin_amdgcn_sdot4(a, b, c, false);
#else
  int s = c;
  s += ((int)(a << 24) >> 24) * ((int)(b << 24) >> 24);
  s += ((int)(a << 16) >> 24) * ((int)(b << 16) >> 24);
  s += ((int)(a << 8) >> 24) * ((int)(b << 8) >> 24);
  s += ((int)a >> 24) * ((int)b >> 24);
  return s;
#endif
}
__device__ __forceinline__ float sigm(float x) { return 1.f / (1.f + __expf(-x)); }
__device__ __forceinline__ float ftanh(float x) { float t = __expf(2.f * x); return (t - 1.f) / (t + 1.f); }
__device__ __forceinline__ u16 f2h(float x) { return __builtin_bit_cast(u16, (f16)x); }
__device__ __forceinline__ float h2f(u16 x) { return (float)__builtin_bit_cast(f16, x); }
__device__ __forceinline__ void async_load16(const u16* g, u16* l) {
  __builtin_amdgcn_global_load_lds((const __attribute__((address_space(1))) u32*)g,
                                   (__attribute__((address_space(3))) u32*)l, 16, 0, 0);
}

// ---------------- small utility kernels ----------------

__global__ __launch_bounds__(64) void k_zero(float* __restrict__ accum) {
  if (threadIdx.x < 8) accum[threadIdx.x] = 0.f;
}

__global__ __launch_bounds__(256) void k_nb(const float* __restrict__ bows, float* __restrict__ nb) {
  __shared__ float red[256];
  const int b = blockIdx.x, tid = threadIdx.x;
  float s = 0.f;
  for (int v = tid; v < 10000; v += 256) s += bows[b * 10000 + v];
  red[tid] = s; __syncthreads();
  for (int o = 128; o > 0; o >>= 1) { if (tid < o) red[tid] += red[tid + o]; __syncthreads(); }
  const float inv = 1.f / red[0];
  for (int v = tid; v < 10000; v += 256) nb[b * 10000 + v] = bows[b * 10000 + v] * inv;
}

__global__ __launch_bounds__(256) void k_bsum(const float* __restrict__ a, const float* __restrict__ b,
                                              float* __restrict__ o, int n) {
  int i = blockIdx.x * 256 + threadIdx.x;
  if (i < n) o[i] = a[i] + b[i];
}

__global__ __launch_bounds__(256) void k_fill(float* __restrict__ C, const float* __restrict__ bias,
                                              int N, int total) {
  for (int i = blockIdx.x * 256 + threadIdx.x; i < total; i += gridDim.x * 256)
    C[i] = bias[i % N];
}

// stack two 50-vectors into one 100-vector
__global__ __launch_bounds__(128) void k_stack2(const float* __restrict__ a, const float* __restrict__ b,
                                                float* __restrict__ o) {
  const int t = threadIdx.x;
  if (t < 50) o[t] = a[t];
  else if (t < 100) o[t] = b[t - 50];
}

// sum Z partial slices + bias, optional ReLU. P[z][total], out[total].
template<int EPI>   // 1: +bias, 2: +bias+relu
__global__ __launch_bounds__(256) void k_reduceZ(const float* __restrict__ P,
                                                 const float* __restrict__ bias,
                                                 float* __restrict__ out,
                                                 int N, int total, int Z) {
  for (int i = blockIdx.x * 256 + threadIdx.x; i < total; i += gridDim.x * 256) {
    float s = bias[i % N];
    for (int z = 0; z < Z; ++z) s += P[(size_t)z * total + i];
    if (EPI == 2) s = s > 0.f ? s : 0.f;
    out[i] = s;
  }
}

// quantize Whh rows to int8, row-major layout whq[layer][row][52 dwords]
__global__ __launch_bounds__(64) void k_quant_whh(const float* __restrict__ Whh,
                                                  u32* __restrict__ whq, float* __restrict__ rowscale) {
  const int gr = blockIdx.x;          // 0..2399
  const int lane = threadIdx.x;
  __shared__ float wrow[200];
  const float* src = Whh + (size_t)gr * 200;
  float m = 0.f;
  for (int c = lane; c < 200; c += 64) { float v = src[c]; wrow[c] = v; m = fmaxf(m, fabsf(v)); }
  for (int o = 32; o > 0; o >>= 1) m = fmaxf(m, __shfl_down(m, o));
  m = __shfl(m, 0);
  const float qs = (m > 0.f) ? 127.f / m : 0.f;
  __syncthreads();
  const int l = gr / 800, rr = gr - l * 800;
  if (lane < 52) {
    u32 d = 0;
    if (lane < 50) {
#pragma unroll
      for (int b = 0; b < 4; ++b) {
        int q = __float2int_rn(wrow[lane * 4 + b] * qs);
        q = max(-127, min(127, q));
        d |= ((u32)(q & 0xff)) << (8 * b);
      }
    }
    whq[l * 41600 + rr * 52 + lane] = d;
  }
  if (lane == 0) rowscale[gr] = (m > 0.f) ? m / 127.f : 0.f;
}

// bf16 staging for the beta MFMA GEMM
__global__ __launch_bounds__(256) void k_prep_A(const float* __restrict__ muq, u16* __restrict__ Abf) {
  int idx = blockIdx.x * 256 + threadIdx.x;
  if (idx >= 5120 * 320) return;
  int r = idx % 320, m = idx / 320;
  float v = 0.f;
  if (r < 300 && m < 5000) { int t = m / 50, k = m - t * 50; v = muq[k * 30000 + t * 300 + r]; }
  Abf[idx] = f2bf(v);
}
__global__ __launch_bounds__(256) void k_prep_B(const float* __restrict__ rho, u16* __restrict__ Bbf) {
  int idx = blockIdx.x * 256 + threadIdx.x;
  if (idx >= 10112 * 320) return;
  int r = idx % 320, n = idx / 320;
  float v = (r < 300 && n < 10000) ? rho[n * 300 + r] : 0.f;
  Bbf[idx] = f2bf(v);
}

// ---------------- fp32 GEMM, 64x64 tile: C[M,N] = A[M,K] @ B[N,K]^T ----------------

#define ST 64
#define SBK 32

template<int AMODE, int BMODE, int EPI>
__global__ __launch_bounds__(256) void gemm64(
    const float* __restrict__ A, const float* __restrict__ Bm, const float* __restrict__ Bm2,
    const float* __restrict__ bias, float* __restrict__ C,
    int M, int N, int Kd, int lda, int ldb,
    const int* __restrict__ times, const float* __restrict__ etas)
{
  __shared__ __align__(16) float As[SBK][ST + 4];   // row stride 272B = 16B-aligned
  __shared__ __align__(16) float Bs[SBK][ST + 4];
  const int tid = threadIdx.x;
  const int tx = tid & 15, ty = tid >> 4;
  const int m_base = blockIdx.x * ST, n_base = blockIdx.y * ST;
  float acc[4][4] = {};
  const int nkt = (Kd + SBK - 1) / SBK;
  const int per = (nkt + gridDim.z - 1) / gridDim.z;
  const int kt0 = blockIdx.z * per;
  const int kt1 = min(nkt, kt0 + per);
  const int lkk = tid & 31;      // k within tile (consecutive lanes -> coalesced global)
  const int lrow = tid >> 5;     // 0..7
  for (int kt = kt0; kt < kt1; ++kt) {
    const int kg = kt * SBK + lkk;
#pragma unroll
    for (int i = 0; i < 8; ++i) {
      const int m = m_base + lrow + i * 8;
      float v = 0.f;
      if (m < M && kg < Kd) {
        if (AMODE == 0) v = A[(size_t)m * lda + kg];
        else {
          if (kg < 10000) v = A[(size_t)m * 10000 + kg];
          else v = etas[times[m] * 50 + (kg - 10000)];
        }
      }
      As[lkk][lrow + i * 8] = v;
    }
#pragma unroll
    for (int i = 0; i < 8; ++i) {
      const int n = n_base + lrow + i * 8;
      float v = 0.f;
      if (n < N && kg < Kd) {
        if (BMODE == 0) v = Bm[(size_t)n * ldb + kg];
        else v = (n < 50) ? Bm[(size_t)n * ldb + kg] : Bm2[(size_t)(n - 50) * ldb + kg];
      }
      Bs[lkk][lrow + i * 8] = v;
    }
    __syncthreads();
#pragma unroll
    for (int kk = 0; kk < SBK; ++kk) {
      const float4 a4 = *(const float4*)&As[kk][ty * 4];
      const float4 b4 = *(const float4*)&Bs[kk][tx * 4];
      const float av[4] = {a4.x, a4.y, a4.z, a4.w};
      const float bv[4] = {b4.x, b4.y, b4.z, b4.w};
#pragma unroll
      for (int i = 0; i < 4; ++i)
#pragma unroll
        for (int j = 0; j < 4; ++j) acc[i][j] += av[i] * bv[j];
    }
    __syncthreads();
  }
#pragma unroll
  for (int i = 0; i < 4; ++i) {
    const int m = m_base + ty * 4 + i;
    if (m >= M) continue;
#pragma unroll
    for (int j = 0; j < 4; ++j) {
      const int n = n_base + tx * 4 + j;
      if (n >= N) continue;
      float v = acc[i][j];
      if (EPI == 1) { C[(size_t)m * N + n] = v + bias[n]; }
      else if (EPI == 2) { v += bias[n]; C[(size_t)m * N + n] = v > 0.f ? v : 0.f; }
      else if (EPI == 5) { atomicAdd(&C[(size_t)m * N + n], v); }
      else { C[(size_t)m * N + n] = v; }
    }
  }
}

// ---------------- fp32 GEMM, 128x128 tile, 8x8 micro, reg-prefetch, ------------
// ---------------- split-K partials to P[z][M][N] with plain stores ------------

#define LT 128
#define LBK 32

template<int AMODE>
__global__ __launch_bounds__(256) void gemm128p(
    const float* __restrict__ A, const float* __restrict__ Bm,
    float* __restrict__ P,          // [gridDim.z][M][N]
    int M, int N, int Kd, int lda, int ldb,
    const int* __restrict__ times, const float* __restrict__ etas)
{
  __shared__ __align__(16) float As[LBK][LT + 4];   // row stride 528B = 16B-aligned
  __shared__ __align__(16) float Bs[LBK][LT + 4];
  const int tid = threadIdx.x;
  const int tx = tid & 15, ty = tid >> 4;
  const int m_base = blockIdx.x * LT, n_base = blockIdx.y * LT;
  const int nkt = (Kd + LBK - 1) / LBK;
  const int per = (nkt + gridDim.z - 1) / gridDim.z;
  const int kt0 = blockIdx.z * per;
  const int kt1 = min(nkt, kt0 + per);
  const int lkk = tid & 31;        // k within tile (coalesced global)
  const int lrow = tid >> 5;       // 0..7
  float acc[8][8] = {};
  float pa[16], pb[16];
  {
    const int kg = kt0 * LBK + lkk;   // kt0 may exceed nkt: kg>=Kd -> zeros (slice stays valid)
#pragma unroll
    for (int i = 0; i < 16; ++i) {
      const int m = m_base + lrow + i * 8;
      float v = 0.f;
      if (m < M && kg < Kd) {
        if (AMODE == 0) v = A[(size_t)m * lda + kg];
        else v = (kg < 10000) ? A[(size_t)m * 10000 + kg] : etas[times[m] * 50 + (kg - 10000)];
      }
      pa[i] = v;
      const int n = n_base + lrow + i * 8;
      float w = 0.f;
      if (n < N && kg < Kd) w = Bm[(size_t)n * ldb + kg];
      pb[i] = w;
    }
  }
  for (int kt = kt0; kt < kt1; ++kt) {
#pragma unroll
    for (int i = 0; i < 16; ++i) {
      As[lkk][lrow + i * 8] = pa[i];
      Bs[lkk][lrow + i * 8] = pb[i];
    }
    __syncthreads();
    if (kt + 1 < kt1) {
      const int kg = (kt + 1) * LBK + lkk;
#pragma unroll
      for (int i = 0; i < 16; ++i) {
        const int m = m_base + lrow + i * 8;
        float v = 0.f;
        if (m < M && kg < Kd) {
          if (AMODE == 0) v = A[(size_t)m * lda + kg];
          else v = (kg < 10000) ? A[(size_t)m * 10000 + kg] : etas[times[m] * 50 + (kg - 10000)];
        }
        pa[i] = v;
        const int n = n_base + lrow + i * 8;
        float w = 0.f;
        if (n < N && kg < Kd) w = Bm[(size_t)n * ldb + kg];
        pb[i] = w;
      }
    }
#pragma unroll
    for (int kk = 0; kk < LBK; ++kk) {
      const float4* ap = (const float4*)&As[kk][ty * 8];
      const float4* bp = (const float4*)&Bs[kk][tx * 8];
      const float4 a0 = ap[0], a1 = ap[1];
      const float4 b0 = bp[0], b1 = bp[1];
      const float av[8] = {a0.x, a0.y, a0.z, a0.w, a1.x, a1.y, a1.z, a1.w};
      const float bv[8] = {b0.x, b0.y, b0.z, b0.w, b1.x, b1.y, b1.z, b1.w};
#pragma unroll
      for (int i = 0; i < 8; ++i)
#pragma unroll
        for (int j = 0; j < 8; ++j) acc[i][j] += av[i] * bv[j];
    }
    __syncthreads();
  }
  float* Cz = P + (size_t)blockIdx.z * M * N;
#pragma unroll
  for (int i = 0; i < 8; ++i) {
    const int m = m_base + ty * 8 + i;
    if (m >= M) continue;
#pragma unroll
    for (int j = 0; j < 8; ++j) {
      const int n = n_base + tx * 8 + j;
      if (n >= N) continue;
      Cz[(size_t)m * N + n] = acc[i][j];
    }
  }
}

// ---------------- beta GEMM: bf16 MFMA ----------------

__global__ __launch_bounds__(256) void gemm_mfma_bT(
    const u16* __restrict__ A, const u16* __restrict__ B, u16* __restrict__ C,
    int M, int N)
{
  __shared__ u16 As[128 * 32];
  __shared__ u16 Bs[128 * 32];
  const int tid = threadIdx.x;
  const int l = tid & 63, w = tid >> 6;
  const int wm = w & 1, wn = w >> 1;
  const int m0 = blockIdx.x * 128, n0 = blockIdx.y * 128;
  f32x4 acc[4][4] = {};
  const int arow = l >> 2;
  const int acol = (l & 3) * 8;
  for (int kt = 0; kt < 10; ++kt) {
    const int k0 = kt * 32;
#pragma unroll
    for (int c = 0; c < 2; ++c) {
      const int i = w + c * 4;
      async_load16(A + (size_t)(m0 + i * 16 + arow) * 320 + k0 + acol, As + i * 512);
      async_load16(B + (size_t)(n0 + i * 16 + arow) * 320 + k0 + acol, Bs + i * 512);
    }
    __syncthreads();
    bf16x8 af[4], bfr[4];
#pragma unroll
    for (int x = 0; x < 4; ++x) {
      af[x]  = *(const bf16x8*)&As[(wm * 64 + x * 16 + (l & 15)) * 32 + (l >> 4) * 8];
      bfr[x] = *(const bf16x8*)&Bs[(wn * 64 + x * 16 + (l & 15)) * 32 + (l >> 4) * 8];
    }
#pragma unroll
    for (int x = 0; x < 4; ++x)
#pragma unroll
      for (int y = 0; y < 4; ++y)
        acc[x][y] = __builtin_amdgcn_mfma_f32_16x16x32_bf16(af[x], bfr[y], acc[x][y], 0, 0, 0);
    __syncthreads();
  }
  const int col = l & 15, quad = l >> 4;
#pragma unroll
  for (int x = 0; x < 4; ++x) {
    const int gmB = m0 + wm * 64 + x * 16 + quad * 4;
#pragma unroll
    for (int y = 0; y < 4; ++y) {
      const int gn = n0 + wn * 64 + y * 16 + col;
      if (gn >= N) continue;
#pragma unroll
      for (int r = 0; r < 4; ++r) {
        const int gm = gmB + r;
        if (gm < M) C[(size_t)gm * N + gn] = f2bf(acc[x][y][r]);
      }
    }
  }
}

// ---------------- LSTM scan: int8 weights REGISTER-resident ----------------

__global__ __launch_bounds__(512, 1) void lstm_scan_reg(
    const u32* __restrict__ whq,       // [800][52] row-major this layer
    const float* __restrict__ rowscale,// [800] this layer
    const float* __restrict__ xproj,   // [100][800]
    float* __restrict__ hseq)          // [100][200]
{
  __shared__ u16 pg[800];                 // gate pre-acts f16
  __shared__ __align__(16) u32 hq[52];    // h int8 packed (200 vals + pad)
  __shared__ float wmax[8];
  __shared__ float hscale_s[1];
  const int tid = threadIdx.x;
  const int act = (tid < 400);
  const int r0 = tid, r1 = tid + 400;
  u32x4 wA4[13], wB4[13];
  float rsA = 0.f, rsB = 0.f;
  float xpA = 0.f, xpB = 0.f;
  if (act) {
    const u32x4* gA = (const u32x4*)(whq + (size_t)r0 * 52);
    const u32x4* gB = (const u32x4*)(whq + (size_t)r1 * 52);
#pragma unroll
    for (int i = 0; i < 13; ++i) { wA4[i] = gA[i]; wB4[i] = gB[i]; }
    rsA = rowscale[r0]; rsB = rowscale[r1];
    xpA = xproj[r0]; xpB = xproj[r1];
  }
  if (tid < 52) hq[tid] = 0;
  if (tid < 8) wmax[tid] = 0.f;
  if (tid == 0) hscale_s[0] = 0.f;
  float c_reg = 0.f;
  __syncthreads();
  for (int t = 0; t < 100; ++t) {
    if (act) {
      float nxA = 0.f, nxB = 0.f;
      if (t < 99) { nxA = xproj[(t + 1) * 800 + r0]; nxB = xproj[(t + 1) * 800 + r1]; }
      const float hdq = hscale_s[0];
      u32x4 hv4[13];
#pragma unroll
      for (int i = 0; i < 13; ++i) hv4[i] = *((const u32x4*)hq + i);
      int aA = 0, aB = 0;
#pragma unroll
      for (int g = 0; g < 50; ++g) {
        const u32 h = hv4[g >> 2][g & 3];
        aA = dot4i8(wA4[g >> 2][g & 3], h, aA);
        aB = dot4i8(wB4[g >> 2][g & 3], h, aB);
      }
      pg[r0] = f2h((float)aA * (rsA * hdq) + xpA);
      pg[r1] = f2h((float)aB * (rsB * hdq) + xpB);
      xpA = nxA; xpB = nxB;
    }
    __syncthreads();   // pg ready; all lanes done reading hq/hscale
    float hv = 0.f;
    if (tid < 200) {
      float gi = sigm(h2f(pg[tid]));
      float gf = sigm(h2f(pg[200 + tid]));
      float gg = ftanh(h2f(pg[400 + tid]));
      float go = sigm(h2f(pg[600 + tid]));
      c_reg = gf * c_reg + gi * gg;
      hv = go * ftanh(c_reg);
      hseq[t * 200 + tid] = hv;
    }
    // block-wide max|h| (only waves 0-3 hold h; others contribute 0)
    float m = fabsf(hv);
    for (int o = 32; o > 0; o >>= 1) m = fmaxf(m, __shfl_down(m, o));
    if ((tid & 63) == 0) wmax[tid >> 6] = m;
    __syncthreads();   // wmax ready, pg consumed
    if (tid < 200) {
      const float hm = fmaxf(fmaxf(wmax[0], wmax[1]), fmaxf(wmax[2], wmax[3]));
      const float qs = (hm > 0.f) ? 127.f / hm : 0.f;
      int q = __float2int_rn(hv * qs);
      q = max(-127, min(127, q));
      ((signed char*)hq)[tid] = (signed char)q;
      if (tid == 0) hscale_s[0] = (hm > 0.f) ? hm / 127.f : 0.f;
    }
    __syncthreads();   // hq + hscale ready for next step
  }
}

// ---------------- eta scan: 50-col recurrent tail, ONE wave ----------------

__global__ __launch_bounds__(64, 1) void eta_scan_reg(
    const float* __restrict__ muW, const float* __restrict__ lsW,  // [50][250] fp32
    const float* __restrict__ pc0,   // [100][100] (bias included)
    float* __restrict__ etas, float* __restrict__ accum)
{
  __shared__ __align__(16) float ep[52];
  const int j = threadIdx.x;
  const int act = (j < 50);
  float wmu[52], wls[52];
  if (act) {
#pragma unroll
    for (int k = 0; k < 25; ++k) {   // rows start at j*250+200: even offset -> 8B aligned
      float2 a = *(const float2*)(muW + (size_t)j * 250 + 200 + 2 * k);
      float2 b = *(const float2*)(lsW + (size_t)j * 250 + 200 + 2 * k);
      wmu[2 * k] = a.x; wmu[2 * k + 1] = a.y;
      wls[2 * k] = b.x; wls[2 * k + 1] = b.y;
    }
    wmu[50] = wmu[51] = wls[50] = wls[51] = 0.f;
  } else {
#pragma unroll
    for (int k = 0; k < 52; ++k) { wmu[k] = 0.f; wls[k] = 0.f; }
  }
  if (j < 52) ep[j] = 0.f;
  float klacc = 0.f;
  float mye = 0.f;                       // this lane's eta_prev
  float pmu = act ? pc0[j] : 0.f;        // prefetched pc0 row t
  float pls_ = act ? pc0[50 + j] : 0.f;
  __syncthreads();
  for (int t = 0; t < 100; ++t) {
    float nmu = 0.f, nls = 0.f;
    if (act && t < 99) { nmu = pc0[(t + 1) * 100 + j]; nls = pc0[(t + 1) * 100 + 50 + j]; }
    float ma[4] = {pmu, 0.f, 0.f, 0.f};
    float la[4] = {pls_, 0.f, 0.f, 0.f};
    const float4* e4 = (const float4*)ep;
#pragma unroll
    for (int i = 0; i < 13; ++i) {
      const float4 e = e4[i];
      ma[0] += wmu[4 * i + 0] * e.x; ma[1] += wmu[4 * i + 1] * e.y;
      ma[2] += wmu[4 * i + 2] * e.z; ma[3] += wmu[4 * i + 3] * e.w;
      la[0] += wls[4 * i + 0] * e.x; la[1] += wls[4 * i + 1] * e.y;
      la[2] += wls[4 * i + 2] * e.z; la[3] += wls[4 * i + 3] * e.w;
    }
    const float mu = (ma[0] + ma[1]) + (ma[2] + ma[3]);
    const float ls = (la[0] + la[1]) + (la[2] + la[3]);
    __syncthreads();   // all lanes done reading ep (lockstep anyway; fence)
    if (act) {
      const float pls = (t == 0) ? 0.f : LOG_DELTA;
      const float pv = __expf(pls) + 1e-6f;
      const float d = mu - mye;
      klacc += 0.5f * ((__expf(ls) + d * d) / pv - 1.f + pls - ls);
      etas[t * 50 + j] = mu;
      mye = mu;
      ep[j] = mu;
    }
    __syncthreads();   // ep ready for next step
    pmu = nmu; pls_ = nls;
  }
  for (int o = 32; o > 0; o >>= 1) klacc += __shfl_down(klacc, o);
  if (j == 0) accum[0] = klacc;
}

// ---------------- theta head (reads stacked [128][100] mu|ls) ----------------

__global__ __launch_bounds__(64) void k_theta(const float* __restrict__ mul,
                                              const float* __restrict__ etas, const int* __restrict__ times,
                                              float* __restrict__ theta, float* __restrict__ accum) {
  const int b = blockIdx.x, lane = threadIdx.x;
  float m_ = 0.f, l_ = 0.f, e_ = 0.f, mx = -1e30f;
  if (lane < 50) {
    m_ = mul[b * 100 + lane];
    l_ = mul[b * 100 + 50 + lane];
    e_ = etas[times[b] * 50 + lane];
    mx = m_;
  }
  for (int o = 32; o > 0; o >>= 1) mx = fmaxf(mx, __shfl_down(mx, o));
  mx = __shfl(mx, 0);
  float ex = (lane < 50) ? __expf(m_ - mx) : 0.f;
  float sum = ex;
  for (int o = 32; o > 0; o >>= 1) sum += __shfl_down(sum, o);
  sum = __shfl(sum, 0);
  if (lane < 50) theta[b * 50 + lane] = ex / sum;
  float kl = 0.f;
  if (lane < 50) {
    float d = m_ - e_;
    kl = 0.5f * ((__expf(l_) + d * d) / (1.f + 1e-6f) - 1.f - l_);
  }
  for (int o = 32; o > 0; o >>= 1) kl += __shfl_down(kl, o);
  if (lane == 0) atomicAdd(accum + 1, kl);
}

// ---------------- softmax denominators ----------------

__global__ __launch_bounds__(256) void k_rowsum(const u16* __restrict__ logit, float* __restrict__ Z) {
  const int r = blockIdx.x, tid = threadIdx.x;
  const u32* row = (const u32*)(logit + (size_t)r * 10000);
  __shared__ float red[256];
  float s = 0.f;
  for (int v = tid; v < 5000; v += 256) {
    u32 p = row[v];
    s += __expf(bf2f((u16)(p & 0xffffu))) + __expf(bf2f((u16)(p >> 16)));
  }
  red[tid] = s; __syncthreads();
  for (int o = 128; o > 0; o >>= 1) { if (tid < o) red[tid] += red[tid + o]; __syncthreads(); }
  if (tid == 0) Z[r] = red[0];
}

// ---------------- NLL ----------------

__global__ __launch_bounds__(256) void k_nll(const u16* __restrict__ logit, const float* __restrict__ Z,
                                             const float* __restrict__ theta, const float* __restrict__ bows,
                                             const int* __restrict__ times, float* __restrict__ accum) {
  const int b = blockIdx.x, seg = blockIdx.y, tid = threadIdx.x;
  const int t = times[b];
  __shared__ float c2[52];
  __shared__ float red[256];
  if (tid < 50) c2[tid] = theta[b * 50 + tid] / Z[t * 50 + tid];
  __syncthreads();
  float part = 0.f;
  const int v0 = seg * 1250, v1 = v0 + 1250;
  const u16* base = logit + (size_t)t * 500000;
  for (int v = v0 + tid; v < v1; v += 256) {
    float ssv = 1e-12f;
#pragma unroll
    for (int k = 0; k < 50; ++k) ssv += c2[k] * __expf(bf2f(base[k * 10000 + v]));
    part += bows[b * 10000 + v] * __logf(ssv);
  }
  red[tid] = part; __syncthreads();
  for (int o = 128; o > 0; o >>= 1) { if (tid < o) red[tid] += red[tid + o]; __syncthreads(); }
  if (tid == 0) atomicAdd(accum + 3, -red[0]);
}

// ---------------- kl_alpha ----------------

__global__ __launch_bounds__(256) void k_alpha_kl(const float* __restrict__ muq, const float* __restrict__ lsq,
                                                  float* __restrict__ accum) {
  __shared__ float red[256];
  const int tid = threadIdx.x;
  float s = 0.f;
  for (int i = blockIdx.x * 256 + tid; i < 1500000; i += gridDim.x * 256) {
    int r = i % 300;
    int tk = i / 300;
    int k = tk % 50;
    int t = tk / 50;
    size_t idx = (size_t)k * 30000 + (size_t)t * 300 + r;
    float mu = muq[idx], ls = lsq[idx];
    float pm = 0.f, pls = 0.f;
    if (t > 0) { pm = muq[idx - 300]; pls = LOG_DELTA; }
    float d = mu - pm;
    s += 0.5f * ((__expf(ls) + d * d) / (__expf(pls) + 1e-6f) - 1.f + pls - ls);
  }
  red[tid] = s; __syncthreads();
  for (int o = 128; o > 0; o >>= 1) { if (tid < o) red[tid] += red[tid + o]; __syncthreads(); }
  if (tid == 0) atomicAdd(accum + 2, red[0]);
}

// ---------------- final combine ----------------

__global__ __launch_bounds__(64) void k_final(const float* __restrict__ accum, float* __restrict__ out) {
  if (threadIdx.x == 0) {
    float nll = accum[3] * COEFF;
    float kl_eta = accum[0];
    float kl_theta = accum[1] * COEFF;
    float kl_alpha = accum[2];
    out[0] = nll + kl_eta + kl_theta + kl_alpha;
    out[1] = nll;
    out[2] = kl_eta;
    out[3] = kl_theta;
    out[4] = kl_alpha;
  }
}

// ---------------- launcher ----------------

extern "C" void kernel_launch(void* const* d_in, const int* in_sizes, int n_in,
                              void* d_out, int out_size, void* d_ws, size_t ws_size,
                              hipStream_t stream) {
  (void)in_sizes; (void)n_in; (void)out_size; (void)ws_size;
  const float* bows   = (const float*)d_in[0];
  const int*   times  = (const int*)d_in[1];
  const float* rnn_in = (const float*)d_in[2];
  const float* rho_W  = (const float*)d_in[3];
  const float* muq    = (const float*)d_in[4];
  const float* lsq    = (const float*)d_in[5];
  const float* qW1    = (const float*)d_in[6];
  const float* qb1    = (const float*)d_in[7];
  const float* qW2    = (const float*)d_in[8];
  const float* qb2    = (const float*)d_in[9];
  const float* muthW  = (const float*)d_in[10];
  const float* muthb  = (const float*)d_in[11];
  const float* lsthW  = (const float*)d_in[12];
  const float* lsthb  = (const float*)d_in[13];
  const float* emW    = (const float*)d_in[14];
  const float* emb    = (const float*)d_in[15];
  const float* Wih    = (const float*)d_in[16];
  const float* Whh    = (const float*)d_in[17];
  const float* bih    = (const float*)d_in[18];
  const float* bhh    = (const float*)d_in[19];
  const float* mueW   = (const float*)d_in[20];
  const float* mueb   = (const float*)d_in[21];
  const float* lseW   = (const float*)d_in[22];
  const float* lseb   = (const float*)d_in[23];
  float* out = (float*)d_out;
  float* ws = (float*)d_ws;

  float* accum = ws + 0;
  float* nb    = ws + 8;
  float* x0    = ws + 1280008;
  float* xproj = ws + 1300008;
  float* hsA   = ws + 1380008;
  float* hsB   = ws + 1400008;
  u32*   whq   = (u32*)(ws + 1420008);         // 124,800 u32 (3 layers, [800][52])
  float* rowsc = ws + 1544808;                 // 2400
  float* bias2 = ws + 1547208;                 // 100 (stacked mu/ls theta bias)
  float* pc0   = ws + 1547408;                 // [100][100] eta-head o_t part
  float* bias2e= ws + 1558008;                 // 100 (stacked eta-head bias)
  float* hsC   = ws + 1560008;                 // 20,000
  float* bsum  = ws + 1660008;
  float* etas  = ws + 1662408;
  float* h1    = ws + 1667408;
  float* h2    = ws + 1769808;
  float* mul   = ws + 1872208;                 // [128][100] stacked mu_t|ls_t
  float* theta = ws + 1885008;
  float* Zrow  = ws + 1891408;
  u16*   A_bf  = (u16*)(ws + 1896408);
  u16*   B_bf  = (u16*)(ws + 2715608);
  u16*   logit = (u16*)(ws + 4333528);
  // split-K partial buffers: alias the logit region (logit written later,
  // by gemm_mfma_bT, after all reduces are done)
  float* P1    = ws + 4333528;                 // theta1: 45 x 102400 = 4,608,000
  float* Px0   = ws + 8941528;                 // x0:     64 x  20000 = 1,280,000
  float* P2    = ws + 10221528;                // theta2:  5 x 102400 =   512,000

  k_zero<<<1, 64, 0, stream>>>(accum);
  k_nb<<<128, 256, 0, stream>>>(bows, nb);
  k_quant_whh<<<2400, 64, 0, stream>>>(Whh, whq, rowsc);
  k_bsum<<<10, 256, 0, stream>>>(bih, bhh, bsum, 2400);
  k_prep_A<<<6400, 256, 0, stream>>>(muq, A_bf);
  k_prep_B<<<12640, 256, 0, stream>>>(rho_W, B_bf);
  k_stack2<<<1, 128, 0, stream>>>(muthb, lsthb, bias2);
  k_stack2<<<1, 128, 0, stream>>>(mueb, lseb, bias2e);
  k_fill<<<40, 256, 0, stream>>>(pc0, bias2e, 100, 10000);

  // x0 = rnn_inp @ eta_map_W^T + eta_map_b   (partials + reduce)
  gemm128p<0><<<dim3(1, 2, 64), 256, 0, stream>>>(rnn_in, emW, Px0,
                                                  100, 200, 10000, 10000, 10000, nullptr, nullptr);
  k_reduceZ<1><<<79, 256, 0, stream>>>(Px0, emb, x0, 200, 20000, 64);

  // LSTM layers (register-resident int8 scans)
  const float* lin[3] = {x0, hsA, hsB};
  float* lout[3] = {hsA, hsB, hsC};
  for (int l = 0; l < 3; ++l) {
    gemm64<0, 0, 1><<<dim3(2, 13, 1), 256, 0, stream>>>(lin[l], Wih + l * 160000, nullptr,
                                                        bsum + l * 800, xproj,
                                                        100, 800, 200, 200, 200, nullptr, nullptr);
    lstm_scan_reg<<<1, 512, 0, stream>>>(whq + l * 41600, rowsc + l * 800, xproj, lout[l]);
  }
  // eta head: parallel o_t GEMM (pc0 += hsC @ W[:, :200]^T), then 1-wave scan
  gemm64<0, 1, 5><<<dim3(2, 2, 7), 256, 0, stream>>>(hsC, mueW, lseW, nullptr, pc0,
                                                     100, 100, 200, 200, 250, nullptr, nullptr);
  eta_scan_reg<<<1, 64, 0, stream>>>(mueW, lseW, pc0, etas, accum);

  // theta encoder (partials + fused bias/relu reduce)
  gemm128p<2><<<dim3(1, 7, 45), 256, 0, stream>>>(nb, qW1, P1,
                                                  128, 800, 10050, 10000, 10050, times, etas);
  k_reduceZ<2><<<400, 256, 0, stream>>>(P1, qb1, h1, 800, 102400, 45);
  gemm128p<0><<<dim3(1, 7, 5), 256, 0, stream>>>(h1, qW2, P2,
                                                 128, 800, 800, 800, 800, nullptr, nullptr);
  k_reduceZ<2><<<400, 256, 0, stream>>>(P2, qb2, h2, 800, 102400, 5);
  // fused mu/ls head -> stacked [128][100]
  k_fill<<<50, 256, 0, stream>>>(mul, bias2, 100, 12800);
  gemm64<0, 1, 5><<<dim3(2, 2, 5), 256, 0, stream>>>(h2, muthW, lsthW, nullptr, mul,
                                                     128, 100, 800, 800, 800, nullptr, nullptr);
  k_theta<<<128, 64, 0, stream>>>(mul, etas, times, theta, accum);

  // beta logits (bf16 MFMA) + softmax denominators + NLL
  gemm_mfma_bT<<<dim3(40, 79), 256, 0, stream>>>(A_bf, B_bf, logit, 5000, 10000);
  k_rowsum<<<5000, 256, 0, stream>>>(logit, Zrow);
  k_nll<<<dim3(128, 8), 256, 0, stream>>>(logit, Zrow, theta, bows, times, accum);

  k_alpha_kl<<<512, 256, 0, stream>>>(muq, lsq, accum);
  k_final<<<1, 64, 0, stream>>>(accum, out);
}